// Round 3
// baseline (768.568 us; speedup 1.0000x reference)
//
#include <hip/hip_runtime.h>
#include <hip/hip_bf16.h>
#include <stdint.h>

#define NN 50000
#define NE 800000
#define DD 128
#define NCHUNK 3125      // NN/16 (gemm row-chunks)
#define NBKT 782         // ceil(NN/64) dst buckets of 64 nodes
#define BCH 4096         // edges per workgroup in bucket kernels
#define BGRID ((NE + BCH - 1) / BCH)   // 196

typedef __attribute__((ext_vector_type(8))) unsigned short ushort8;

__device__ inline uint16_t f2bf(float f) {            // RNE f32->bf16
    uint32_t u = __float_as_uint(f);
    return (uint16_t)((u + 0x7fffu + ((u >> 16) & 1u)) >> 16);
}
__device__ inline float bf_lo(uint32_t u) { return __uint_as_float(u << 16); }
__device__ inline float bf_hi(uint32_t u) { return __uint_as_float(u & 0xffff0000u); }

// ---------- W transpose ----------
__global__ __launch_bounds__(256) void transpose_w_k(const float* __restrict__ W,
                                                     float* __restrict__ Wt) {
    int i = blockIdx.x * 256 + threadIdx.x;
    if (i < DD * DD) {
        int j = i >> 7, k = i & 127;
        Wt[k * DD + j] = W[i];
    }
}

// ---------- GEMM: h = x @ W^T (f32 compute, bf16 store) + s/d projections ----------
__global__ __launch_bounds__(256) void gemm_h_k(const float* __restrict__ x,
                                                const float* __restrict__ Wt,
                                                const float* __restrict__ a,
                                                uint16_t* __restrict__ hb,
                                                float* __restrict__ sArr,
                                                float* __restrict__ dArr) {
    __shared__ float xs[4][16 * 132];
    const int tid = threadIdx.x;
    const int wid = tid >> 6;
    const int l   = tid & 63;
    const int chunk = blockIdx.x * 4 + wid;
    if (chunk >= NCHUNK) return;
    const int r0 = chunk * 16;
    const int cg = l & 15, rg = l >> 4;
    const int c0 = cg * 8;
    float* xw = xs[wid];
    const float* xg = x + (size_t)r0 * DD;
    #pragma unroll
    for (int i = 0; i < 8; ++i) {
        int idx = (i * 64 + l) * 4;
        float4 v = *(const float4*)(xg + idx);
        int row = idx >> 7, col = idx & 127;
        *(float4*)(xw + row * 132 + col) = v;
    }
    float acc[4][8];
    #pragma unroll
    for (int rr = 0; rr < 4; ++rr)
        #pragma unroll
        for (int c = 0; c < 8; ++c) acc[rr][c] = 0.f;

    const float* wp = Wt + c0;
    const float* xr = xw + rg * 4 * 132;
    #pragma unroll 2
    for (int k = 0; k < DD; k += 4) {
        float4 xv[4];
        #pragma unroll
        for (int rr = 0; rr < 4; ++rr) xv[rr] = *(const float4*)(xr + rr * 132 + k);
        #pragma unroll
        for (int kk = 0; kk < 4; ++kk) {
            float4 w0 = *(const float4*)(wp + (k + kk) * DD);
            float4 w1 = *(const float4*)(wp + (k + kk) * DD + 4);
            float wv[8] = {w0.x, w0.y, w0.z, w0.w, w1.x, w1.y, w1.z, w1.w};
            #pragma unroll
            for (int rr = 0; rr < 4; ++rr) {
                float xk = (kk == 0) ? xv[rr].x : (kk == 1) ? xv[rr].y
                         : (kk == 2) ? xv[rr].z : xv[rr].w;
                #pragma unroll
                for (int c = 0; c < 8; ++c) acc[rr][c] = fmaf(xk, wv[c], acc[rr][c]);
            }
        }
    }
    float as_[8], ad_[8];
    #pragma unroll
    for (int c = 0; c < 8; ++c) { as_[c] = a[c0 + c]; ad_[c] = a[DD + c0 + c]; }
    #pragma unroll
    for (int rr = 0; rr < 4; ++rr) {
        float ps = 0.f, pd = 0.f;
        #pragma unroll
        for (int c = 0; c < 8; ++c) {
            ps = fmaf(acc[rr][c], as_[c], ps);
            pd = fmaf(acc[rr][c], ad_[c], pd);
        }
        #pragma unroll
        for (int o = 8; o > 0; o >>= 1) {
            ps += __shfl_xor(ps, o);
            pd += __shfl_xor(pd, o);
        }
        int row = r0 + rg * 4 + rr;
        if (cg == 0) { sArr[row] = ps; dArr[row] = pd; }
        ushort8 hv;
        #pragma unroll
        for (int c = 0; c < 8; ++c) hv[c] = f2bf(acc[rr][c]);
        *(ushort8*)(hb + (size_t)row * DD + c0) = hv;
    }
}

// ---------- B1: bucket counts via LDS histogram ----------
__global__ __launch_bounds__(256) void bcount_k(const int* __restrict__ dst,
                                                int* __restrict__ cnt) {
    __shared__ int lh[NBKT];
    int t = threadIdx.x;
    for (int k = t; k < NBKT; k += 256) lh[k] = 0;
    __syncthreads();
    int base = blockIdx.x * BCH;
    #pragma unroll
    for (int i = 0; i < 16; ++i) {
        int idx = base + i * 256 + t;
        if (idx < NE) atomicAdd(&lh[dst[idx] >> 6], 1);
    }
    __syncthreads();
    for (int k = t; k < NBKT; k += 256) if (lh[k]) atomicAdd(&cnt[k], lh[k]);
}

// ---------- B2: exclusive scan of 782 counts -> off, cur ----------
__global__ __launch_bounds__(256) void bscan_k(const int* __restrict__ cnt,
                                               int* __restrict__ off,
                                               int* __restrict__ cur) {
    __shared__ unsigned wsum[4];
    __shared__ unsigned wbase[4];
    int t = threadIdx.x, l = t & 63, w = t >> 6;
    unsigned v[4]; unsigned s = 0;
    #pragma unroll
    for (int k = 0; k < 4; ++k) {
        int idx = t * 4 + k;
        v[k] = (idx < NBKT) ? (unsigned)cnt[idx] : 0u;
        s += v[k];
    }
    unsigned inc = s;
    #pragma unroll
    for (int o = 1; o < 64; o <<= 1) {
        unsigned n = __shfl_up(inc, o);
        if (l >= o) inc += n;
    }
    if (l == 63) wsum[w] = inc;
    __syncthreads();
    if (t == 0) {
        unsigned r = 0;
        for (int k = 0; k < 4; ++k) { unsigned c = wsum[k]; wbase[k] = r; r += c; }
    }
    __syncthreads();
    unsigned run = wbase[w] + (inc - s);
    #pragma unroll
    for (int k = 0; k < 4; ++k) {
        int idx = t * 4 + k;
        if (idx < NBKT) { off[idx] = (int)run; cur[idx] = (int)run; }
        run += v[k];
    }
    if (t == 255) off[NBKT] = NE;
}

// ---------- B3: multisplit scatter with per-bucket contiguous reservation ----------
// record: .x = (src<<6)|(dst&63), .y = bits of e
__global__ __launch_bounds__(256) void bscat_k(const int* __restrict__ src,
                                               const int* __restrict__ dst,
                                               const float* __restrict__ sA,
                                               const float* __restrict__ dA,
                                               int* __restrict__ cur,
                                               uint2* __restrict__ rec) {
    __shared__ int lh[NBKT];
    __shared__ int gc[NBKT];
    int t = threadIdx.x;
    for (int k = t; k < NBKT; k += 256) lh[k] = 0;
    __syncthreads();
    int base = blockIdx.x * BCH;
    unsigned pk[16]; int bk[16]; float ev[16];
    #pragma unroll
    for (int i = 0; i < 16; ++i) {
        int idx = base + i * 256 + t;
        if (idx < NE) {
            int s_ = src[idx], d_ = dst[idx];
            bk[i] = d_ >> 6;
            pk[i] = ((unsigned)s_ << 6) | (unsigned)(d_ & 63);
            float z = sA[s_] + dA[d_];
            ev[i] = 1.f / (1.f + __expf(-z));
            atomicAdd(&lh[bk[i]], 1);
        } else bk[i] = -1;
    }
    __syncthreads();
    for (int k = t; k < NBKT; k += 256) {
        int c = lh[k];
        if (c) gc[k] = atomicAdd(&cur[k], c);
    }
    __syncthreads();
    #pragma unroll
    for (int i = 0; i < 16; ++i) {
        if (bk[i] >= 0) {
            int p = atomicAdd(&gc[bk[i]], 1);
            rec[p] = make_uint2(pk[i], __float_as_uint(ev[i]));
        }
    }
}

// ---------- agg: one WG per 64-node bucket, LDS f32 accumulate ----------
__global__ __launch_bounds__(256) void agg_k(const uint32_t* __restrict__ hb,
                                             const int* __restrict__ off,
                                             const uint2* __restrict__ rec,
                                             float* __restrict__ out) {
    __shared__ float acc[64 * 128];   // 32 KB; node d: col 2l -> word d*128+l, col 2l+1 -> word d*128+64+l
    int t = threadIdx.x, l = t & 63, wid = t >> 6;
    float4 z4 = {0.f, 0.f, 0.f, 0.f};
    #pragma unroll
    for (int k = 0; k < 8; ++k) *(float4*)&acc[(k * 256 + t) * 4] = z4;
    __syncthreads();
    int b = blockIdx.x;
    int beg = off[b], end = off[b + 1];
    int j = beg + wid;
    while (j + 4 < end) {
        uint2 r0 = rec[j], r1 = rec[j + 4];
        uint32_t u0 = hb[(size_t)(r0.x >> 6) * 64 + l];
        uint32_t u1 = hb[(size_t)(r1.x >> 6) * 64 + l];
        float e0 = __uint_as_float(r0.y), e1 = __uint_as_float(r1.y);
        int d0 = (int)(r0.x & 63), d1 = (int)(r1.x & 63);
        atomicAdd(&acc[d0 * 128 + l],      e0 * bf_lo(u0));
        atomicAdd(&acc[d0 * 128 + 64 + l], e0 * bf_hi(u0));
        atomicAdd(&acc[d1 * 128 + l],      e1 * bf_lo(u1));
        atomicAdd(&acc[d1 * 128 + 64 + l], e1 * bf_hi(u1));
        j += 8;
    }
    while (j < end) {
        uint2 r0 = rec[j];
        uint32_t u0 = hb[(size_t)(r0.x >> 6) * 64 + l];
        float e0 = __uint_as_float(r0.y);
        int d0 = (int)(r0.x & 63);
        atomicAdd(&acc[d0 * 128 + l],      e0 * bf_lo(u0));
        atomicAdd(&acc[d0 * 128 + 64 + l], e0 * bf_hi(u0));
        j += 4;
    }
    __syncthreads();
    int n0 = b * 64;
    #pragma unroll
    for (int r = 0; r < 16; ++r) {
        int row = wid + r * 4;
        if (n0 + row < NN) {
            float2 v;
            v.x = acc[row * 128 + l];
            v.y = acc[row * 128 + 64 + l];
            ((float2*)out)[(size_t)(n0 + row) * 64 + l] = v;
        }
    }
}

// ---------- fallback: direct atomic scatter-add ----------
__global__ __launch_bounds__(256) void edge_atomic_k(const int* __restrict__ src, const int* __restrict__ dst,
                                                     const float* __restrict__ sArr, const float* __restrict__ dArr,
                                                     const uint32_t* __restrict__ hb, float* __restrict__ out) {
    int wid = threadIdx.x >> 6, l = threadIdx.x & 63;
    int e = blockIdx.x * 4 + wid;
    if (e >= NE) return;
    int sv = src[e], dv = dst[e];
    float z = sArr[sv] + dArr[dv];
    float ev = 1.0f / (1.0f + __expf(-z));
    uint32_t u = hb[(size_t)sv * 64 + l];
    atomicAdd(&out[(size_t)dv * DD + 2 * l],     ev * bf_lo(u));
    atomicAdd(&out[(size_t)dv * DD + 2 * l + 1], ev * bf_hi(u));
}

extern "C" void kernel_launch(void* const* d_in, const int* in_sizes, int n_in,
                              void* d_out, int out_size, void* d_ws, size_t ws_size,
                              hipStream_t stream) {
    const float* x  = (const float*)d_in[0];
    const float* W  = (const float*)d_in[1];
    const float* a  = (const float*)d_in[2];
    const int* src  = (const int*)d_in[3];
    const int* dst  = (const int*)d_in[4];
    float* out = (float*)d_out;

    char* p = (char*)d_ws;
    uint16_t* hb = (uint16_t*)p;            p += (size_t)NN * DD * 2;       // 12.8 MB
    float* Wt    = (float*)p;               p += (size_t)DD * DD * 4;
    float* sA    = (float*)p;               p += (size_t)NN * 4;
    float* dA    = (float*)p;               p += (size_t)NN * 4;
    int*   cnt   = (int*)p;                 p += (size_t)NBKT * 4;
    int*   cur   = (int*)p;                 p += (size_t)NBKT * 4;
    int*   off   = (int*)p;                 p += (size_t)(NBKT + 4) * 4;
    uint2* rec   = (uint2*)(((uintptr_t)p + 15) & ~(uintptr_t)15);
    p = (char*)(rec + NE);                                                   // 6.4 MB
    size_t need  = (size_t)(p - (char*)d_ws);

    if (ws_size >= need) {
        hipMemsetAsync(cnt, 0, sizeof(int) * NBKT, stream);
        transpose_w_k<<<64, 256, 0, stream>>>(W, Wt);
        gemm_h_k<<<(NCHUNK + 3) / 4, 256, 0, stream>>>(x, Wt, a, hb, sA, dA);
        bcount_k<<<BGRID, 256, 0, stream>>>(dst, cnt);
        bscan_k<<<1, 256, 0, stream>>>(cnt, off, cur);
        bscat_k<<<BGRID, 256, 0, stream>>>(src, dst, sA, dA, cur, rec);
        agg_k<<<NBKT, 256, 0, stream>>>((const uint32_t*)hb, off, rec, out);
    } else {
        hipMemsetAsync(out, 0, sizeof(float) * (size_t)NN * DD, stream);
        transpose_w_k<<<64, 256, 0, stream>>>(W, Wt);
        gemm_h_k<<<(NCHUNK + 3) / 4, 256, 0, stream>>>(x, Wt, a, hb, sA, dA);
        edge_atomic_k<<<NE / 4, 256, 0, stream>>>(src, dst, sA, dA, (const uint32_t*)hb, out);
    }
}

// Round 4
// 131.074 us; speedup vs baseline: 5.8636x; 5.8636x over previous
//
#include <hip/hip_runtime.h>
#include <hip/hip_bf16.h>
#include <stdint.h>

#define NN 50000
#define NE 800000
#define DD 128
#define NCHUNK 3125      // NN/16 (gemm row-chunks)
#define NBKT 782         // ceil(NN/64) dst buckets of 64 nodes
#define BCH 4096         // edges per workgroup in bucket kernels
#define BGRID ((NE + BCH - 1) / BCH)   // 196
#define CAP 2048         // per-bucket record capacity for LDS sort (mean 1023, sigma 32)

typedef __attribute__((ext_vector_type(8))) unsigned short ushort8;

__device__ inline uint16_t f2bf(float f) {            // RNE f32->bf16
    uint32_t u = __float_as_uint(f);
    return (uint16_t)((u + 0x7fffu + ((u >> 16) & 1u)) >> 16);
}
__device__ inline float bf_lo(uint32_t u) { return __uint_as_float(u << 16); }
__device__ inline float bf_hi(uint32_t u) { return __uint_as_float(u & 0xffff0000u); }

// ---------- W transpose ----------
__global__ __launch_bounds__(256) void transpose_w_k(const float* __restrict__ W,
                                                     float* __restrict__ Wt) {
    int i = blockIdx.x * 256 + threadIdx.x;
    if (i < DD * DD) {
        int j = i >> 7, k = i & 127;
        Wt[k * DD + j] = W[i];
    }
}

// ---------- GEMM: h = x @ W^T (f32 compute, bf16 store) + s/d projections ----------
__global__ __launch_bounds__(256) void gemm_h_k(const float* __restrict__ x,
                                                const float* __restrict__ Wt,
                                                const float* __restrict__ a,
                                                uint16_t* __restrict__ hb,
                                                float* __restrict__ sArr,
                                                float* __restrict__ dArr) {
    __shared__ float xs[4][16 * 132];
    const int tid = threadIdx.x;
    const int wid = tid >> 6;
    const int l   = tid & 63;
    const int chunk = blockIdx.x * 4 + wid;
    if (chunk >= NCHUNK) return;
    const int r0 = chunk * 16;
    const int cg = l & 15, rg = l >> 4;
    const int c0 = cg * 8;
    float* xw = xs[wid];
    const float* xg = x + (size_t)r0 * DD;
    #pragma unroll
    for (int i = 0; i < 8; ++i) {
        int idx = (i * 64 + l) * 4;
        float4 v = *(const float4*)(xg + idx);
        int row = idx >> 7, col = idx & 127;
        *(float4*)(xw + row * 132 + col) = v;
    }
    float acc[4][8];
    #pragma unroll
    for (int rr = 0; rr < 4; ++rr)
        #pragma unroll
        for (int c = 0; c < 8; ++c) acc[rr][c] = 0.f;

    const float* wp = Wt + c0;
    const float* xr = xw + rg * 4 * 132;
    #pragma unroll 2
    for (int k = 0; k < DD; k += 4) {
        float4 xv[4];
        #pragma unroll
        for (int rr = 0; rr < 4; ++rr) xv[rr] = *(const float4*)(xr + rr * 132 + k);
        #pragma unroll
        for (int kk = 0; kk < 4; ++kk) {
            float4 w0 = *(const float4*)(wp + (k + kk) * DD);
            float4 w1 = *(const float4*)(wp + (k + kk) * DD + 4);
            float wv[8] = {w0.x, w0.y, w0.z, w0.w, w1.x, w1.y, w1.z, w1.w};
            #pragma unroll
            for (int rr = 0; rr < 4; ++rr) {
                float xk = (kk == 0) ? xv[rr].x : (kk == 1) ? xv[rr].y
                         : (kk == 2) ? xv[rr].z : xv[rr].w;
                #pragma unroll
                for (int c = 0; c < 8; ++c) acc[rr][c] = fmaf(xk, wv[c], acc[rr][c]);
            }
        }
    }
    float as_[8], ad_[8];
    #pragma unroll
    for (int c = 0; c < 8; ++c) { as_[c] = a[c0 + c]; ad_[c] = a[DD + c0 + c]; }
    #pragma unroll
    for (int rr = 0; rr < 4; ++rr) {
        float ps = 0.f, pd = 0.f;
        #pragma unroll
        for (int c = 0; c < 8; ++c) {
            ps = fmaf(acc[rr][c], as_[c], ps);
            pd = fmaf(acc[rr][c], ad_[c], pd);
        }
        #pragma unroll
        for (int o = 8; o > 0; o >>= 1) {
            ps += __shfl_xor(ps, o);
            pd += __shfl_xor(pd, o);
        }
        int row = r0 + rg * 4 + rr;
        if (cg == 0) { sArr[row] = ps; dArr[row] = pd; }
        ushort8 hv;
        #pragma unroll
        for (int c = 0; c < 8; ++c) hv[c] = f2bf(acc[rr][c]);
        *(ushort8*)(hb + (size_t)row * DD + c0) = hv;
    }
}

// ---------- B1: bucket counts via LDS histogram ----------
__global__ __launch_bounds__(256) void bcount_k(const int* __restrict__ dst,
                                                int* __restrict__ cnt) {
    __shared__ int lh[NBKT];
    int t = threadIdx.x;
    for (int k = t; k < NBKT; k += 256) lh[k] = 0;
    __syncthreads();
    int base = blockIdx.x * BCH;
    #pragma unroll
    for (int i = 0; i < 16; ++i) {
        int idx = base + i * 256 + t;
        if (idx < NE) atomicAdd(&lh[dst[idx] >> 6], 1);
    }
    __syncthreads();
    for (int k = t; k < NBKT; k += 256) if (lh[k]) atomicAdd(&cnt[k], lh[k]);
}

// ---------- B2: exclusive scan of bucket counts -> off, cur ----------
__global__ __launch_bounds__(256) void bscan_k(const int* __restrict__ cnt,
                                               int* __restrict__ off,
                                               int* __restrict__ cur) {
    __shared__ unsigned wsum[4];
    __shared__ unsigned wbase[4];
    int t = threadIdx.x, l = t & 63, w = t >> 6;
    unsigned v[4]; unsigned s = 0;
    #pragma unroll
    for (int k = 0; k < 4; ++k) {
        int idx = t * 4 + k;
        v[k] = (idx < NBKT) ? (unsigned)cnt[idx] : 0u;
        s += v[k];
    }
    unsigned inc = s;
    #pragma unroll
    for (int o = 1; o < 64; o <<= 1) {
        unsigned n = __shfl_up(inc, o);
        if (l >= o) inc += n;
    }
    if (l == 63) wsum[w] = inc;
    __syncthreads();
    if (t == 0) {
        unsigned r = 0;
        for (int k = 0; k < 4; ++k) { unsigned c = wsum[k]; wbase[k] = r; r += c; }
    }
    __syncthreads();
    unsigned run = wbase[w] + (inc - s);
    #pragma unroll
    for (int k = 0; k < 4; ++k) {
        int idx = t * 4 + k;
        if (idx < NBKT) { off[idx] = (int)run; cur[idx] = (int)run; }
        run += v[k];
    }
    if (t == 255) off[NBKT] = NE;
}

// ---------- B3: multisplit scatter with per-bucket contiguous reservation ----------
// record: .x = (dlocal<<16) | src   (src < 65536, dlocal < 64), .y = bits of e
__global__ __launch_bounds__(256) void bscat_k(const int* __restrict__ src,
                                               const int* __restrict__ dst,
                                               const float* __restrict__ sA,
                                               const float* __restrict__ dA,
                                               int* __restrict__ cur,
                                               uint2* __restrict__ rec) {
    __shared__ int lh[NBKT];
    __shared__ int gc[NBKT];
    int t = threadIdx.x;
    for (int k = t; k < NBKT; k += 256) lh[k] = 0;
    __syncthreads();
    int base = blockIdx.x * BCH;
    unsigned pk[16]; int bk[16]; float ev[16];
    #pragma unroll
    for (int i = 0; i < 16; ++i) {
        int idx = base + i * 256 + t;
        if (idx < NE) {
            int s_ = src[idx], d_ = dst[idx];
            bk[i] = d_ >> 6;
            pk[i] = ((unsigned)(d_ & 63) << 16) | (unsigned)s_;
            float z = sA[s_] + dA[d_];
            ev[i] = 1.f / (1.f + __expf(-z));
            atomicAdd(&lh[bk[i]], 1);
        } else bk[i] = -1;
    }
    __syncthreads();
    for (int k = t; k < NBKT; k += 256) {
        int c = lh[k];
        if (c) gc[k] = atomicAdd(&cur[k], c);
    }
    __syncthreads();
    #pragma unroll
    for (int i = 0; i < 16; ++i) {
        if (bk[i] >= 0) {
            int p = atomicAdd(&gc[bk[i]], 1);
            rec[p] = make_uint2(pk[i], __float_as_uint(ev[i]));
        }
    }
}

// ---------- agg: one WG per bucket; LDS node-sort then per-node wave gather ----------
__global__ __launch_bounds__(256) void bsort_agg_k(const uint32_t* __restrict__ hb,
                                                   const int* __restrict__ off,
                                                   const uint2* __restrict__ rec,
                                                   float* __restrict__ out) {
    __shared__ uint2 srt[CAP];      // 16 KB
    __shared__ int h64[64];
    __shared__ int s65[65];
    __shared__ int curw[64];
    int t = threadIdx.x, l = t & 63, wid = t >> 6;
    int b = blockIdx.x;
    int beg = off[b], end = off[b + 1], cnt = end - beg;
    int n0 = b * 64;
    if (t < 64) h64[t] = 0;
    __syncthreads();

    if (cnt <= CAP) {
        for (int j = t; j < cnt; j += 256) {
            uint2 r = rec[beg + j];
            atomicAdd(&h64[r.x >> 16], 1);
        }
        __syncthreads();
        if (wid == 0) {
            int v = h64[l];
            int inc = v;
            #pragma unroll
            for (int o = 1; o < 64; o <<= 1) {
                int nb = __shfl_up(inc, o);
                if (l >= o) inc += nb;
            }
            s65[l + 1] = inc;
            if (l == 0) s65[0] = 0;
            curw[l] = inc - v;
        }
        __syncthreads();
        for (int j = t; j < cnt; j += 256) {
            uint2 r = rec[beg + j];
            int p = atomicAdd(&curw[r.x >> 16], 1);
            srt[p] = r;
        }
        __syncthreads();
        #pragma unroll 1
        for (int rr = 0; rr < 16; ++rr) {
            int d = wid * 16 + rr;
            int n = n0 + d;
            if (n >= NN) break;
            int js = s65[d], je = s65[d + 1];
            float2 a0 = {0.f,0.f}, a1 = {0.f,0.f}, a2 = {0.f,0.f}, a3 = {0.f,0.f};
            int j = js;
            for (; j + 3 < je; j += 4) {
                uint2 r0 = srt[j], r1 = srt[j+1], r2 = srt[j+2], r3 = srt[j+3];
                uint32_t u0 = hb[(size_t)(r0.x & 0xffffu) * 64 + l];
                uint32_t u1 = hb[(size_t)(r1.x & 0xffffu) * 64 + l];
                uint32_t u2 = hb[(size_t)(r2.x & 0xffffu) * 64 + l];
                uint32_t u3 = hb[(size_t)(r3.x & 0xffffu) * 64 + l];
                float e0 = __uint_as_float(r0.y), e1 = __uint_as_float(r1.y);
                float e2 = __uint_as_float(r2.y), e3 = __uint_as_float(r3.y);
                a0.x = fmaf(e0, bf_lo(u0), a0.x); a0.y = fmaf(e0, bf_hi(u0), a0.y);
                a1.x = fmaf(e1, bf_lo(u1), a1.x); a1.y = fmaf(e1, bf_hi(u1), a1.y);
                a2.x = fmaf(e2, bf_lo(u2), a2.x); a2.y = fmaf(e2, bf_hi(u2), a2.y);
                a3.x = fmaf(e3, bf_lo(u3), a3.x); a3.y = fmaf(e3, bf_hi(u3), a3.y);
            }
            for (; j < je; ++j) {
                uint2 r0 = srt[j];
                uint32_t u0 = hb[(size_t)(r0.x & 0xffffu) * 64 + l];
                float e0 = __uint_as_float(r0.y);
                a0.x = fmaf(e0, bf_lo(u0), a0.x); a0.y = fmaf(e0, bf_hi(u0), a0.y);
            }
            float2 res;
            res.x = (a0.x + a1.x) + (a2.x + a3.x);
            res.y = (a0.y + a1.y) + (a2.y + a3.y);
            ((float2*)out)[(size_t)n * 64 + l] = res;
        }
    } else {
        // overflow-safe path (statistically unreachable: cnt ~ Binom, mean 1023, sigma 32)
        __syncthreads(); __syncthreads(); __syncthreads();
        #pragma unroll 1
        for (int rr = 0; rr < 16; ++rr) {
            int d = wid * 16 + rr;
            int n = n0 + d;
            if (n >= NN) break;
            float2 a0 = {0.f, 0.f};
            for (int j = 0; j < cnt; ++j) {
                uint2 r = rec[beg + j];
                if ((int)(r.x >> 16) == d) {
                    uint32_t u = hb[(size_t)(r.x & 0xffffu) * 64 + l];
                    float e = __uint_as_float(r.y);
                    a0.x = fmaf(e, bf_lo(u), a0.x); a0.y = fmaf(e, bf_hi(u), a0.y);
                }
            }
            ((float2*)out)[(size_t)n * 64 + l] = a0;
        }
    }
}

// ---------- fallback: direct atomic scatter-add ----------
__global__ __launch_bounds__(256) void edge_atomic_k(const int* __restrict__ src, const int* __restrict__ dst,
                                                     const float* __restrict__ sArr, const float* __restrict__ dArr,
                                                     const uint32_t* __restrict__ hb, float* __restrict__ out) {
    int wid = threadIdx.x >> 6, l = threadIdx.x & 63;
    int e = blockIdx.x * 4 + wid;
    if (e >= NE) return;
    int sv = src[e], dv = dst[e];
    float z = sArr[sv] + dArr[dv];
    float ev = 1.0f / (1.0f + __expf(-z));
    uint32_t u = hb[(size_t)sv * 64 + l];
    atomicAdd(&out[(size_t)dv * DD + 2 * l],     ev * bf_lo(u));
    atomicAdd(&out[(size_t)dv * DD + 2 * l + 1], ev * bf_hi(u));
}

extern "C" void kernel_launch(void* const* d_in, const int* in_sizes, int n_in,
                              void* d_out, int out_size, void* d_ws, size_t ws_size,
                              hipStream_t stream) {
    const float* x  = (const float*)d_in[0];
    const float* W  = (const float*)d_in[1];
    const float* a  = (const float*)d_in[2];
    const int* src  = (const int*)d_in[3];
    const int* dst  = (const int*)d_in[4];
    float* out = (float*)d_out;

    char* p = (char*)d_ws;
    uint16_t* hb = (uint16_t*)p;            p += (size_t)NN * DD * 2;       // 12.8 MB
    float* Wt    = (float*)p;               p += (size_t)DD * DD * 4;
    float* sA    = (float*)p;               p += (size_t)NN * 4;
    float* dA    = (float*)p;               p += (size_t)NN * 4;
    int*   cnt   = (int*)p;                 p += (size_t)NBKT * 4;
    int*   cur   = (int*)p;                 p += (size_t)NBKT * 4;
    int*   off   = (int*)p;                 p += (size_t)(NBKT + 4) * 4;
    uint2* rec   = (uint2*)(((uintptr_t)p + 15) & ~(uintptr_t)15);
    p = (char*)(rec + NE);                                                   // 6.4 MB
    size_t need  = (size_t)(p - (char*)d_ws);

    if (ws_size >= need) {
        hipMemsetAsync(cnt, 0, sizeof(int) * NBKT, stream);
        transpose_w_k<<<64, 256, 0, stream>>>(W, Wt);
        gemm_h_k<<<(NCHUNK + 3) / 4, 256, 0, stream>>>(x, Wt, a, hb, sA, dA);
        bcount_k<<<BGRID, 256, 0, stream>>>(dst, cnt);
        bscan_k<<<1, 256, 0, stream>>>(cnt, off, cur);
        bscat_k<<<BGRID, 256, 0, stream>>>(src, dst, sA, dA, cur, rec);
        bsort_agg_k<<<NBKT, 256, 0, stream>>>((const uint32_t*)hb, off, rec, out);
    } else {
        hipMemsetAsync(out, 0, sizeof(float) * (size_t)NN * DD, stream);
        transpose_w_k<<<64, 256, 0, stream>>>(W, Wt);
        gemm_h_k<<<(NCHUNK + 3) / 4, 256, 0, stream>>>(x, Wt, a, hb, sA, dA);
        edge_atomic_k<<<NE / 4, 256, 0, stream>>>(src, dst, sA, dA, (const uint32_t*)hb, out);
    }
}

// Round 5
// 106.445 us; speedup vs baseline: 7.2203x; 1.2314x over previous
//
#include <hip/hip_runtime.h>
#include <hip/hip_bf16.h>
#include <stdint.h>

#define NN 50000
#define NE 800000
#define DD 128
#define NCHUNK 3125      // NN/16 (gemm row-chunks)
#define NBKT 782         // ceil(NN/64) dst buckets of 64 nodes
#define BCH 4096         // edges per workgroup in bscat
#define BGRID ((NE + BCH - 1) / BCH)   // 196
#define CAP 1280         // per-bucket slab capacity (mean 1023, sigma ~32)
#define SPILL_CAP 32768

typedef __attribute__((ext_vector_type(8))) unsigned short ushort8;

__device__ inline uint16_t f2bf(float f) {            // RNE f32->bf16
    uint32_t u = __float_as_uint(f);
    return (uint16_t)((u + 0x7fffu + ((u >> 16) & 1u)) >> 16);
}
__device__ inline float bf_lo(uint32_t u) { return __uint_as_float(u << 16); }
__device__ inline float bf_hi(uint32_t u) { return __uint_as_float(u & 0xffff0000u); }

// ---------- W transpose ----------
__global__ __launch_bounds__(256) void transpose_w_k(const float* __restrict__ W,
                                                     float* __restrict__ Wt) {
    int i = blockIdx.x * 256 + threadIdx.x;
    if (i < DD * DD) {
        int j = i >> 7, k = i & 127;
        Wt[k * DD + j] = W[i];
    }
}

// ---------- GEMM: h = x @ W^T (f32 compute, bf16 store) + s/d projections ----------
__global__ __launch_bounds__(256) void gemm_h_k(const float* __restrict__ x,
                                                const float* __restrict__ Wt,
                                                const float* __restrict__ a,
                                                uint16_t* __restrict__ hb,
                                                float* __restrict__ sArr,
                                                float* __restrict__ dArr) {
    __shared__ float xs[4][16 * 132];
    const int tid = threadIdx.x;
    const int wid = tid >> 6;
    const int l   = tid & 63;
    const int chunk = blockIdx.x * 4 + wid;
    if (chunk >= NCHUNK) return;
    const int r0 = chunk * 16;
    const int cg = l & 15, rg = l >> 4;
    const int c0 = cg * 8;
    float* xw = xs[wid];
    const float* xg = x + (size_t)r0 * DD;
    #pragma unroll
    for (int i = 0; i < 8; ++i) {
        int idx = (i * 64 + l) * 4;
        float4 v = *(const float4*)(xg + idx);
        int row = idx >> 7, col = idx & 127;
        *(float4*)(xw + row * 132 + col) = v;
    }
    float acc[4][8];
    #pragma unroll
    for (int rr = 0; rr < 4; ++rr)
        #pragma unroll
        for (int c = 0; c < 8; ++c) acc[rr][c] = 0.f;

    const float* wp = Wt + c0;
    const float* xr = xw + rg * 4 * 132;
    #pragma unroll 2
    for (int k = 0; k < DD; k += 4) {
        float4 xv[4];
        #pragma unroll
        for (int rr = 0; rr < 4; ++rr) xv[rr] = *(const float4*)(xr + rr * 132 + k);
        #pragma unroll
        for (int kk = 0; kk < 4; ++kk) {
            float4 w0 = *(const float4*)(wp + (k + kk) * DD);
            float4 w1 = *(const float4*)(wp + (k + kk) * DD + 4);
            float wv[8] = {w0.x, w0.y, w0.z, w0.w, w1.x, w1.y, w1.z, w1.w};
            #pragma unroll
            for (int rr = 0; rr < 4; ++rr) {
                float xk = (kk == 0) ? xv[rr].x : (kk == 1) ? xv[rr].y
                         : (kk == 2) ? xv[rr].z : xv[rr].w;
                #pragma unroll
                for (int c = 0; c < 8; ++c) acc[rr][c] = fmaf(xk, wv[c], acc[rr][c]);
            }
        }
    }
    float as_[8], ad_[8];
    #pragma unroll
    for (int c = 0; c < 8; ++c) { as_[c] = a[c0 + c]; ad_[c] = a[DD + c0 + c]; }
    #pragma unroll
    for (int rr = 0; rr < 4; ++rr) {
        float ps = 0.f, pd = 0.f;
        #pragma unroll
        for (int c = 0; c < 8; ++c) {
            ps = fmaf(acc[rr][c], as_[c], ps);
            pd = fmaf(acc[rr][c], ad_[c], pd);
        }
        #pragma unroll
        for (int o = 8; o > 0; o >>= 1) {
            ps += __shfl_xor(ps, o);
            pd += __shfl_xor(pd, o);
        }
        int row = r0 + rg * 4 + rr;
        if (cg == 0) { sArr[row] = ps; dArr[row] = pd; }
        ushort8 hv;
        #pragma unroll
        for (int c = 0; c < 8; ++c) hv[c] = f2bf(acc[rr][c]);
        *(ushort8*)(hb + (size_t)row * DD + c0) = hv;
    }
}

// ---------- bscat: slab scatter. record .x = (dlocal<<16)|src, .y = e bits ----------
__global__ __launch_bounds__(256) void bscat_k(const int* __restrict__ src,
                                               const int* __restrict__ dst,
                                               const float* __restrict__ sA,
                                               const float* __restrict__ dA,
                                               int* __restrict__ cntg,
                                               int* __restrict__ spill_cnt,
                                               uint2* __restrict__ rec,
                                               uint4* __restrict__ spill) {
    __shared__ int lh[NBKT];
    __shared__ int gb[NBKT];
    int t = threadIdx.x;
    for (int k = t; k < NBKT; k += 256) lh[k] = 0;
    __syncthreads();
    int base = blockIdx.x * BCH;
    unsigned pk[16]; int bk[16]; float ev[16];
    #pragma unroll
    for (int i = 0; i < 16; ++i) {
        int idx = base + i * 256 + t;
        if (idx < NE) {
            int s_ = src[idx], d_ = dst[idx];
            bk[i] = d_ >> 6;
            pk[i] = ((unsigned)(d_ & 63) << 16) | (unsigned)s_;
            float z = sA[s_] + dA[d_];
            ev[i] = 1.f / (1.f + __expf(-z));
            atomicAdd(&lh[bk[i]], 1);
        } else bk[i] = -1;
    }
    __syncthreads();
    for (int k = t; k < NBKT; k += 256) {
        int c = lh[k];
        lh[k] = 0;                       // becomes local cursor
        if (c) gb[k] = atomicAdd(&cntg[k], c);
    }
    __syncthreads();
    #pragma unroll
    for (int i = 0; i < 16; ++i) {
        if (bk[i] >= 0) {
            int sl = atomicAdd(&lh[bk[i]], 1);
            int p = gb[bk[i]] + sl;
            if (p < CAP) {
                rec[(size_t)bk[i] * CAP + p] = make_uint2(pk[i], __float_as_uint(ev[i]));
            } else {
                int sp = atomicAdd(spill_cnt, 1);
                if (sp < SPILL_CAP)
                    spill[sp] = make_uint4(pk[i] & 0xffffu,
                                           (unsigned)(bk[i] * 64 + (int)(pk[i] >> 16)),
                                           __float_as_uint(ev[i]), 0u);
            }
        }
    }
}

// ---------- agg: one 512-thread WG per bucket; LDS node-sort then per-node wave gather ----------
__global__ __launch_bounds__(512) void bsort_agg_k(const uint32_t* __restrict__ hb,
                                                   const int* __restrict__ cntg,
                                                   const uint2* __restrict__ rec,
                                                   float* __restrict__ out) {
    __shared__ uint2 srt[CAP];      // 10 KB
    __shared__ int h64[64];
    __shared__ int s65[65];
    __shared__ int curw[64];
    int t = threadIdx.x, l = t & 63, wid = t >> 6;
    int b = blockIdx.x;
    int cnt = cntg[b]; if (cnt > CAP) cnt = CAP;
    int beg = b * CAP;
    int n0 = b * 64;
    if (t < 64) h64[t] = 0;
    __syncthreads();

    for (int j = t; j < cnt; j += 512) {
        uint2 r = rec[beg + j];
        atomicAdd(&h64[r.x >> 16], 1);
    }
    __syncthreads();
    if (wid == 0) {
        int v = h64[l];
        int inc = v;
        #pragma unroll
        for (int o = 1; o < 64; o <<= 1) {
            int nb = __shfl_up(inc, o);
            if (l >= o) inc += nb;
        }
        s65[l + 1] = inc;
        if (l == 0) s65[0] = 0;
        curw[l] = inc - v;
    }
    __syncthreads();
    for (int j = t; j < cnt; j += 512) {
        uint2 r = rec[beg + j];
        int p = atomicAdd(&curw[r.x >> 16], 1);
        srt[p] = r;
    }
    __syncthreads();
    #pragma unroll 1
    for (int rr = 0; rr < 8; ++rr) {
        int d = wid * 8 + rr;
        int n = n0 + d;
        if (n >= NN) break;
        int js = s65[d], je = s65[d + 1];
        float2 a0 = {0.f,0.f}, a1 = {0.f,0.f}, a2 = {0.f,0.f}, a3 = {0.f,0.f};
        int j = js;
        for (; j + 3 < je; j += 4) {
            uint2 r0 = srt[j], r1 = srt[j+1], r2 = srt[j+2], r3 = srt[j+3];
            uint32_t u0 = hb[(size_t)(r0.x & 0xffffu) * 64 + l];
            uint32_t u1 = hb[(size_t)(r1.x & 0xffffu) * 64 + l];
            uint32_t u2 = hb[(size_t)(r2.x & 0xffffu) * 64 + l];
            uint32_t u3 = hb[(size_t)(r3.x & 0xffffu) * 64 + l];
            float e0 = __uint_as_float(r0.y), e1 = __uint_as_float(r1.y);
            float e2 = __uint_as_float(r2.y), e3 = __uint_as_float(r3.y);
            a0.x = fmaf(e0, bf_lo(u0), a0.x); a0.y = fmaf(e0, bf_hi(u0), a0.y);
            a1.x = fmaf(e1, bf_lo(u1), a1.x); a1.y = fmaf(e1, bf_hi(u1), a1.y);
            a2.x = fmaf(e2, bf_lo(u2), a2.x); a2.y = fmaf(e2, bf_hi(u2), a2.y);
            a3.x = fmaf(e3, bf_lo(u3), a3.x); a3.y = fmaf(e3, bf_hi(u3), a3.y);
        }
        for (; j < je; ++j) {
            uint2 r0 = srt[j];
            uint32_t u0 = hb[(size_t)(r0.x & 0xffffu) * 64 + l];
            float e0 = __uint_as_float(r0.y);
            a0.x = fmaf(e0, bf_lo(u0), a0.x); a0.y = fmaf(e0, bf_hi(u0), a0.y);
        }
        float2 res;
        res.x = (a0.x + a1.x) + (a2.x + a3.x);
        res.y = (a0.y + a1.y) + (a2.y + a3.y);
        ((float2*)out)[(size_t)n * 64 + l] = res;
    }
}

// ---------- spill drain (normally 0 records) ----------
__global__ __launch_bounds__(256) void spill_k(const int* __restrict__ spill_cnt,
                                               const uint4* __restrict__ spill,
                                               const uint32_t* __restrict__ hb,
                                               float* __restrict__ out) {
    int n = *spill_cnt; if (n > SPILL_CAP) n = SPILL_CAP;
    int w = blockIdx.x * 4 + (threadIdx.x >> 6), l = threadIdx.x & 63;
    for (int i = w; i < n; i += 32) {
        uint4 r = spill[i];
        uint32_t u = hb[(size_t)r.x * 64 + l];
        float e = __uint_as_float(r.z);
        atomicAdd(&out[(size_t)r.y * DD + 2 * l],     e * bf_lo(u));
        atomicAdd(&out[(size_t)r.y * DD + 2 * l + 1], e * bf_hi(u));
    }
}

// ---------- fallback: direct atomic scatter-add ----------
__global__ __launch_bounds__(256) void edge_atomic_k(const int* __restrict__ src, const int* __restrict__ dst,
                                                     const float* __restrict__ sArr, const float* __restrict__ dArr,
                                                     const uint32_t* __restrict__ hb, float* __restrict__ out) {
    int wid = threadIdx.x >> 6, l = threadIdx.x & 63;
    int e = blockIdx.x * 4 + wid;
    if (e >= NE) return;
    int sv = src[e], dv = dst[e];
    float z = sArr[sv] + dArr[dv];
    float ev = 1.0f / (1.0f + __expf(-z));
    uint32_t u = hb[(size_t)sv * 64 + l];
    atomicAdd(&out[(size_t)dv * DD + 2 * l],     ev * bf_lo(u));
    atomicAdd(&out[(size_t)dv * DD + 2 * l + 1], ev * bf_hi(u));
}

extern "C" void kernel_launch(void* const* d_in, const int* in_sizes, int n_in,
                              void* d_out, int out_size, void* d_ws, size_t ws_size,
                              hipStream_t stream) {
    const float* x  = (const float*)d_in[0];
    const float* W  = (const float*)d_in[1];
    const float* a  = (const float*)d_in[2];
    const int* src  = (const int*)d_in[3];
    const int* dst  = (const int*)d_in[4];
    float* out = (float*)d_out;

    char* p = (char*)d_ws;
    uint16_t* hb = (uint16_t*)p;            p += (size_t)NN * DD * 2;       // 12.8 MB
    float* Wt    = (float*)p;               p += (size_t)DD * DD * 4;
    float* sA    = (float*)p;               p += (size_t)NN * 4;
    float* dA    = (float*)p;               p += (size_t)NN * 4;
    int*   cntg  = (int*)p;                 p += (size_t)NBKT * 4;
    int*   scnt  = (int*)p;                 p += 16;
    uint2* rec   = (uint2*)(((uintptr_t)p + 15) & ~(uintptr_t)15);
    p = (char*)(rec + (size_t)NBKT * CAP);                                   // 8.0 MB
    uint4* spill = (uint4*)p;               p += (size_t)SPILL_CAP * 16;     // 0.5 MB
    size_t need  = (size_t)(p - (char*)d_ws);

    if (ws_size >= need) {
        hipMemsetAsync(cntg, 0, sizeof(int) * NBKT + 16, stream);
        transpose_w_k<<<64, 256, 0, stream>>>(W, Wt);
        gemm_h_k<<<(NCHUNK + 3) / 4, 256, 0, stream>>>(x, Wt, a, hb, sA, dA);
        bscat_k<<<BGRID, 256, 0, stream>>>(src, dst, sA, dA, cntg, scnt, rec, spill);
        bsort_agg_k<<<NBKT, 512, 0, stream>>>((const uint32_t*)hb, cntg, rec, out);
        spill_k<<<8, 256, 0, stream>>>(scnt, spill, (const uint32_t*)hb, out);
    } else {
        hipMemsetAsync(out, 0, sizeof(float) * (size_t)NN * DD, stream);
        transpose_w_k<<<64, 256, 0, stream>>>(W, Wt);
        gemm_h_k<<<(NCHUNK + 3) / 4, 256, 0, stream>>>(x, Wt, a, hb, sA, dA);
        edge_atomic_k<<<NE / 4, 256, 0, stream>>>(src, dst, sA, dA, (const uint32_t*)hb, out);
    }
}

// Round 6
// 92.031 us; speedup vs baseline: 8.3512x; 1.1566x over previous
//
#include <hip/hip_runtime.h>
#include <hip/hip_bf16.h>
#include <stdint.h>

#define NN 50000
#define NE 800000
#define DD 128
#define NBKT 782         // ceil(NN/64) dst buckets of 64 nodes
#define BCH 4096         // edges per workgroup in bscat
#define BGRID ((NE + BCH - 1) / BCH)   // 196
#define CAP 1280         // per-bucket slab capacity (mean 1023, sigma ~32)
#define SPILL_CAP 32768
#define GROWS 32         // gemm rows per block
#define GGRID ((NN + GROWS - 1) / GROWS)  // 1563

typedef __attribute__((ext_vector_type(8))) unsigned short ushort8;
typedef __attribute__((ext_vector_type(8))) short short8;
typedef __attribute__((ext_vector_type(4))) float f32x4;

__device__ inline uint16_t f2bf(float f) {            // RNE f32->bf16
    uint32_t u = __float_as_uint(f);
    return (uint16_t)((u + 0x7fffu + ((u >> 16) & 1u)) >> 16);
}
__device__ inline float bf_lo(uint32_t u) { return __uint_as_float(u << 16); }
__device__ inline float bf_hi(uint32_t u) { return __uint_as_float(u & 0xffff0000u); }

// ---------- W f32 -> bf16 (row-major [j][k], same layout as input W) ----------
__global__ __launch_bounds__(256) void wconv_k(const float* __restrict__ W,
                                               uint16_t* __restrict__ Wb) {
    int i = blockIdx.x * 256 + threadIdx.x;
    if (i < DD * DD) Wb[i] = f2bf(W[i]);
}

// ---------- MFMA GEMM: h = x @ W^T (bf16 mfma, f32 acc) + s/d projections ----------
// block: 32 rows x 128 cols, 4 waves. wave (wid): rows (wid>>1)*16, cols (wid&1)*64 (4 tiles).
// A frag (16x32 tile): lane l holds row l&15, k = (l>>4)*8 .. +8 (contiguous).
// B frag: lane l holds col l&15, k = (l>>4)*8 .. +8  -> W row-major is contiguous in k.
// C/D: col = l&15, row = (l>>4)*4 + reg  [m89-verified].
__global__ __launch_bounds__(256) void gemm_mfma_k(const float* __restrict__ x,
                                                   const uint16_t* __restrict__ Wb,
                                                   const float* __restrict__ a,
                                                   uint16_t* __restrict__ hb,
                                                   float* __restrict__ sArr,
                                                   float* __restrict__ dArr) {
    __shared__ __align__(16) uint16_t hs[GROWS][136];   // padded: +8 bf16/row
    __shared__ float sdl[2 * GROWS];
    const int t = threadIdx.x, l = t & 63, wid = t >> 6;
    const int r0 = blockIdx.x * GROWS;
    const int wr0 = (wid >> 1) * 16;
    const int wc0 = (wid & 1) * 64;
    const int lr = l & 15, lk = l >> 4;
    if (t < 2 * GROWS) sdl[t] = 0.f;
    __syncthreads();

    f32x4 acc[4] = {{0.f,0.f,0.f,0.f},{0.f,0.f,0.f,0.f},{0.f,0.f,0.f,0.f},{0.f,0.f,0.f,0.f}};
    const int arow = r0 + wr0 + lr;
    const bool rok = arow < NN;
    const float* xp = x + (size_t)arow * DD + lk * 8;

    #pragma unroll
    for (int kc = 0; kc < 4; ++kc) {
        short8 af;
        if (rok) {
            float4 v0 = *(const float4*)(xp + kc * 32);
            float4 v1 = *(const float4*)(xp + kc * 32 + 4);
            af[0] = (short)f2bf(v0.x); af[1] = (short)f2bf(v0.y);
            af[2] = (short)f2bf(v0.z); af[3] = (short)f2bf(v0.w);
            af[4] = (short)f2bf(v1.x); af[5] = (short)f2bf(v1.y);
            af[6] = (short)f2bf(v1.z); af[7] = (short)f2bf(v1.w);
        } else {
            af = short8{0,0,0,0,0,0,0,0};
        }
        #pragma unroll
        for (int c = 0; c < 4; ++c) {
            int col = wc0 + c * 16 + lr;
            short8 bf_ = *(const short8*)(Wb + (size_t)col * DD + kc * 32 + lk * 8);
            acc[c] = __builtin_amdgcn_mfma_f32_16x16x32_bf16(af, bf_, acc[c], 0, 0, 0);
        }
    }

    // s/d partials from f32 accumulators
    float avs[4], avd[4];
    #pragma unroll
    for (int c = 0; c < 4; ++c) {
        avs[c] = a[wc0 + c * 16 + lr];
        avd[c] = a[DD + wc0 + c * 16 + lr];
    }
    #pragma unroll
    for (int i = 0; i < 4; ++i) {
        float ps = 0.f, pd = 0.f;
        #pragma unroll
        for (int c = 0; c < 4; ++c) {
            ps = fmaf(acc[c][i], avs[c], ps);
            pd = fmaf(acc[c][i], avd[c], pd);
        }
        #pragma unroll
        for (int o = 8; o > 0; o >>= 1) {
            ps += __shfl_xor(ps, o);
            pd += __shfl_xor(pd, o);
        }
        if (lr == 0) {
            int brow = wr0 + lk * 4 + i;
            atomicAdd(&sdl[brow], ps);
            atomicAdd(&sdl[GROWS + brow], pd);
        }
    }
    // h -> LDS (bf16)
    #pragma unroll
    for (int c = 0; c < 4; ++c)
        #pragma unroll
        for (int i = 0; i < 4; ++i)
            hs[wr0 + lk * 4 + i][wc0 + c * 16 + lr] = f2bf(acc[c][i]);
    __syncthreads();

    // coalesced writeback: thread t -> row t>>3, cols (t&7)*16 .. +16
    {
        int row = t >> 3, colg = (t & 7) * 16;
        int grow = r0 + row;
        if (grow < NN) {
            ushort8 v0 = *(const ushort8*)&hs[row][colg];
            ushort8 v1 = *(const ushort8*)&hs[row][colg + 8];
            *(ushort8*)(hb + (size_t)grow * DD + colg) = v0;
            *(ushort8*)(hb + (size_t)grow * DD + colg + 8) = v1;
        }
    }
    if (t < GROWS) {
        int grow = r0 + t;
        if (grow < NN) { sArr[grow] = sdl[t]; dArr[grow] = sdl[GROWS + t]; }
    }
}

// ---------- bscat: slab scatter. record .x = (dlocal<<16)|src, .y = e bits ----------
__global__ __launch_bounds__(256) void bscat_k(const int* __restrict__ src,
                                               const int* __restrict__ dst,
                                               const float* __restrict__ sA,
                                               const float* __restrict__ dA,
                                               int* __restrict__ cntg,
                                               int* __restrict__ spill_cnt,
                                               uint2* __restrict__ rec,
                                               uint4* __restrict__ spill) {
    __shared__ int lh[NBKT];
    __shared__ int gb[NBKT];
    int t = threadIdx.x;
    for (int k = t; k < NBKT; k += 256) lh[k] = 0;
    __syncthreads();
    int base = blockIdx.x * BCH;
    unsigned pk[16]; int bk[16]; float ev[16];
    #pragma unroll
    for (int i = 0; i < 16; ++i) {
        int idx = base + i * 256 + t;
        if (idx < NE) {
            int s_ = src[idx], d_ = dst[idx];
            bk[i] = d_ >> 6;
            pk[i] = ((unsigned)(d_ & 63) << 16) | (unsigned)s_;
            float z = sA[s_] + dA[d_];
            ev[i] = 1.f / (1.f + __expf(-z));
            atomicAdd(&lh[bk[i]], 1);
        } else bk[i] = -1;
    }
    __syncthreads();
    for (int k = t; k < NBKT; k += 256) {
        int c = lh[k];
        lh[k] = 0;                       // becomes local cursor
        if (c) gb[k] = atomicAdd(&cntg[k], c);
    }
    __syncthreads();
    #pragma unroll
    for (int i = 0; i < 16; ++i) {
        if (bk[i] >= 0) {
            int sl = atomicAdd(&lh[bk[i]], 1);
            int p = gb[bk[i]] + sl;
            if (p < CAP) {
                rec[(size_t)bk[i] * CAP + p] = make_uint2(pk[i], __float_as_uint(ev[i]));
            } else {
                int sp = atomicAdd(spill_cnt, 1);
                if (sp < SPILL_CAP)
                    spill[sp] = make_uint4(pk[i] & 0xffffu,
                                           (unsigned)(bk[i] * 64 + (int)(pk[i] >> 16)),
                                           __float_as_uint(ev[i]), 0u);
            }
        }
    }
}

// ---------- agg: one 512-thread WG per bucket; LDS node-sort then per-node wave gather ----------
__global__ __launch_bounds__(512) void bsort_agg_k(const uint32_t* __restrict__ hb,
                                                   const int* __restrict__ cntg,
                                                   const uint2* __restrict__ rec,
                                                   float* __restrict__ out) {
    __shared__ uint2 srt[CAP];      // 10 KB
    __shared__ int h64[64];
    __shared__ int s65[65];
    __shared__ int curw[64];
    int t = threadIdx.x, l = t & 63, wid = t >> 6;
    int b = blockIdx.x;
    int cnt = cntg[b]; if (cnt > CAP) cnt = CAP;
    int beg = b * CAP;
    int n0 = b * 64;
    if (t < 64) h64[t] = 0;
    __syncthreads();

    for (int j = t; j < cnt; j += 512) {
        uint2 r = rec[beg + j];
        atomicAdd(&h64[r.x >> 16], 1);
    }
    __syncthreads();
    if (wid == 0) {
        int v = h64[l];
        int inc = v;
        #pragma unroll
        for (int o = 1; o < 64; o <<= 1) {
            int nb = __shfl_up(inc, o);
            if (l >= o) inc += nb;
        }
        s65[l + 1] = inc;
        if (l == 0) s65[0] = 0;
        curw[l] = inc - v;
    }
    __syncthreads();
    for (int j = t; j < cnt; j += 512) {
        uint2 r = rec[beg + j];
        int p = atomicAdd(&curw[r.x >> 16], 1);
        srt[p] = r;
    }
    __syncthreads();
    #pragma unroll 1
    for (int rr = 0; rr < 8; ++rr) {
        int d = wid * 8 + rr;
        int n = n0 + d;
        if (n >= NN) break;
        int js = s65[d], je = s65[d + 1];
        float2 a0 = {0.f,0.f}, a1 = {0.f,0.f}, a2 = {0.f,0.f}, a3 = {0.f,0.f};
        int j = js;
        for (; j + 3 < je; j += 4) {
            uint2 r0 = srt[j], r1 = srt[j+1], r2 = srt[j+2], r3 = srt[j+3];
            uint32_t u0 = hb[(size_t)(r0.x & 0xffffu) * 64 + l];
            uint32_t u1 = hb[(size_t)(r1.x & 0xffffu) * 64 + l];
            uint32_t u2 = hb[(size_t)(r2.x & 0xffffu) * 64 + l];
            uint32_t u3 = hb[(size_t)(r3.x & 0xffffu) * 64 + l];
            float e0 = __uint_as_float(r0.y), e1 = __uint_as_float(r1.y);
            float e2 = __uint_as_float(r2.y), e3 = __uint_as_float(r3.y);
            a0.x = fmaf(e0, bf_lo(u0), a0.x); a0.y = fmaf(e0, bf_hi(u0), a0.y);
            a1.x = fmaf(e1, bf_lo(u1), a1.x); a1.y = fmaf(e1, bf_hi(u1), a1.y);
            a2.x = fmaf(e2, bf_lo(u2), a2.x); a2.y = fmaf(e2, bf_hi(u2), a2.y);
            a3.x = fmaf(e3, bf_lo(u3), a3.x); a3.y = fmaf(e3, bf_hi(u3), a3.y);
        }
        for (; j < je; ++j) {
            uint2 r0 = srt[j];
            uint32_t u0 = hb[(size_t)(r0.x & 0xffffu) * 64 + l];
            float e0 = __uint_as_float(r0.y);
            a0.x = fmaf(e0, bf_lo(u0), a0.x); a0.y = fmaf(e0, bf_hi(u0), a0.y);
        }
        float2 res;
        res.x = (a0.x + a1.x) + (a2.x + a3.x);
        res.y = (a0.y + a1.y) + (a2.y + a3.y);
        ((float2*)out)[(size_t)n * 64 + l] = res;
    }
}

// ---------- spill drain (normally 0 records) ----------
__global__ __launch_bounds__(256) void spill_k(const int* __restrict__ spill_cnt,
                                               const uint4* __restrict__ spill,
                                               const uint32_t* __restrict__ hb,
                                               float* __restrict__ out) {
    int n = *spill_cnt; if (n > SPILL_CAP) n = SPILL_CAP;
    int w = blockIdx.x * 4 + (threadIdx.x >> 6), l = threadIdx.x & 63;
    for (int i = w; i < n; i += 32) {
        uint4 r = spill[i];
        uint32_t u = hb[(size_t)r.x * 64 + l];
        float e = __uint_as_float(r.z);
        atomicAdd(&out[(size_t)r.y * DD + 2 * l],     e * bf_lo(u));
        atomicAdd(&out[(size_t)r.y * DD + 2 * l + 1], e * bf_hi(u));
    }
}

// ---------- fallback: direct atomic scatter-add ----------
__global__ __launch_bounds__(256) void edge_atomic_k(const int* __restrict__ src, const int* __restrict__ dst,
                                                     const float* __restrict__ sArr, const float* __restrict__ dArr,
                                                     const uint32_t* __restrict__ hb, float* __restrict__ out) {
    int wid = threadIdx.x >> 6, l = threadIdx.x & 63;
    int e = blockIdx.x * 4 + wid;
    if (e >= NE) return;
    int sv = src[e], dv = dst[e];
    float z = sArr[sv] + dArr[dv];
    float ev = 1.0f / (1.0f + __expf(-z));
    uint32_t u = hb[(size_t)sv * 64 + l];
    atomicAdd(&out[(size_t)dv * DD + 2 * l],     ev * bf_lo(u));
    atomicAdd(&out[(size_t)dv * DD + 2 * l + 1], ev * bf_hi(u));
}

extern "C" void kernel_launch(void* const* d_in, const int* in_sizes, int n_in,
                              void* d_out, int out_size, void* d_ws, size_t ws_size,
                              hipStream_t stream) {
    const float* x  = (const float*)d_in[0];
    const float* W  = (const float*)d_in[1];
    const float* a  = (const float*)d_in[2];
    const int* src  = (const int*)d_in[3];
    const int* dst  = (const int*)d_in[4];
    float* out = (float*)d_out;

    char* p = (char*)d_ws;
    uint16_t* hb = (uint16_t*)p;            p += (size_t)NN * DD * 2;       // 12.8 MB
    uint16_t* Wb = (uint16_t*)p;            p += (size_t)DD * DD * 2;       // 32 KB
    float* sA    = (float*)p;               p += (size_t)NN * 4;
    float* dA    = (float*)p;               p += (size_t)NN * 4;
    int*   cntg  = (int*)p;                 p += (size_t)NBKT * 4;
    int*   scnt  = (int*)p;                 p += 16;
    uint2* rec   = (uint2*)(((uintptr_t)p + 15) & ~(uintptr_t)15);
    p = (char*)(rec + (size_t)NBKT * CAP);                                   // 8.0 MB
    uint4* spill = (uint4*)p;               p += (size_t)SPILL_CAP * 16;     // 0.5 MB
    size_t need  = (size_t)(p - (char*)d_ws);

    if (ws_size >= need) {
        hipMemsetAsync(cntg, 0, sizeof(int) * NBKT + 16, stream);
        wconv_k<<<64, 256, 0, stream>>>(W, Wb);
        gemm_mfma_k<<<GGRID, 256, 0, stream>>>(x, Wb, a, hb, sA, dA);
        bscat_k<<<BGRID, 256, 0, stream>>>(src, dst, sA, dA, cntg, scnt, rec, spill);
        bsort_agg_k<<<NBKT, 512, 0, stream>>>((const uint32_t*)hb, cntg, rec, out);
        spill_k<<<8, 256, 0, stream>>>(scnt, spill, (const uint32_t*)hb, out);
    } else {
        hipMemsetAsync(out, 0, sizeof(float) * (size_t)NN * DD, stream);
        wconv_k<<<64, 256, 0, stream>>>(W, Wb);
        gemm_mfma_k<<<GGRID, 256, 0, stream>>>(x, Wb, a, hb, sA, dA);
        edge_atomic_k<<<NE / 4, 256, 0, stream>>>(src, dst, sA, dA, (const uint32_t*)hb, out);
    }
}

// Round 7
// 88.046 us; speedup vs baseline: 8.7292x; 1.0453x over previous
//
#include <hip/hip_runtime.h>
#include <hip/hip_bf16.h>
#include <stdint.h>

#define NN 50000
#define NE 800000
#define DD 128
#define NBKT 782         // ceil(NN/64) dst buckets of 64 nodes
#define BCH 4096         // edges per workgroup in bscat
#define BGRID ((NE + BCH - 1) / BCH)   // 196
#define CAP 1280         // per-bucket slab capacity (mean 1023, sigma ~32)
#define SPILL_CAP 32768
#define GROWS 32         // gemm rows per block
#define GGRID ((NN + GROWS - 1) / GROWS)  // 1563

typedef __attribute__((ext_vector_type(8))) unsigned short ushort8;
typedef __attribute__((ext_vector_type(8))) short short8;
typedef __attribute__((ext_vector_type(4))) float f32x4;

__device__ inline uint16_t f2bf(float f) {            // RNE f32->bf16
    uint32_t u = __float_as_uint(f);
    return (uint16_t)((u + 0x7fffu + ((u >> 16) & 1u)) >> 16);
}
__device__ inline float bf_lo(uint32_t u) { return __uint_as_float(u << 16); }
__device__ inline float bf_hi(uint32_t u) { return __uint_as_float(u & 0xffff0000u); }

// ---------- W f32 -> bf16 (row-major [j][k]) + zero the bucket counters ----------
__global__ __launch_bounds__(256) void wconv_k(const float* __restrict__ W,
                                               uint16_t* __restrict__ Wb,
                                               int* __restrict__ cntg) {
    int t = threadIdx.x;
    if (blockIdx.x == 0) {                         // zero cntg[NBKT] + scnt (contiguous)
        for (int k = t; k < NBKT + 4; k += 256) cntg[k] = 0;
    }
    int i = blockIdx.x * 256 + t;
    if (i < DD * DD) Wb[i] = f2bf(W[i]);
}

// ---------- MFMA GEMM: h = x @ W^T (bf16 mfma, f32 acc) + s/d projections ----------
// block: 32 rows x 128 cols, 4 waves. wave (wid): rows (wid>>1)*16, cols (wid&1)*64 (4 tiles).
// A frag (16x32 tile): lane l holds row l&15, k = (l>>4)*8 .. +8 (contiguous).
// B frag: lane l holds col l&15, k = (l>>4)*8 .. +8  -> W row-major is contiguous in k.
// C/D: col = l&15, row = (l>>4)*4 + reg  [m89-verified].
__global__ __launch_bounds__(256) void gemm_mfma_k(const float* __restrict__ x,
                                                   const uint16_t* __restrict__ Wb,
                                                   const float* __restrict__ a,
                                                   uint16_t* __restrict__ hb,
                                                   float* __restrict__ sArr,
                                                   float* __restrict__ dArr) {
    __shared__ __align__(16) uint16_t hs[GROWS][136];   // padded: +8 bf16/row
    __shared__ float sdl[2 * GROWS];
    const int t = threadIdx.x, l = t & 63, wid = t >> 6;
    const int r0 = blockIdx.x * GROWS;
    const int wr0 = (wid >> 1) * 16;
    const int wc0 = (wid & 1) * 64;
    const int lr = l & 15, lk = l >> 4;
    if (t < 2 * GROWS) sdl[t] = 0.f;
    __syncthreads();

    f32x4 acc[4] = {{0.f,0.f,0.f,0.f},{0.f,0.f,0.f,0.f},{0.f,0.f,0.f,0.f},{0.f,0.f,0.f,0.f}};
    const int arow = r0 + wr0 + lr;
    const bool rok = arow < NN;
    const float* xp = x + (size_t)arow * DD + lk * 8;

    #pragma unroll
    for (int kc = 0; kc < 4; ++kc) {
        short8 af;
        if (rok) {
            float4 v0 = *(const float4*)(xp + kc * 32);
            float4 v1 = *(const float4*)(xp + kc * 32 + 4);
            af[0] = (short)f2bf(v0.x); af[1] = (short)f2bf(v0.y);
            af[2] = (short)f2bf(v0.z); af[3] = (short)f2bf(v0.w);
            af[4] = (short)f2bf(v1.x); af[5] = (short)f2bf(v1.y);
            af[6] = (short)f2bf(v1.z); af[7] = (short)f2bf(v1.w);
        } else {
            af = short8{0,0,0,0,0,0,0,0};
        }
        #pragma unroll
        for (int c = 0; c < 4; ++c) {
            int col = wc0 + c * 16 + lr;
            short8 bf_ = *(const short8*)(Wb + (size_t)col * DD + kc * 32 + lk * 8);
            acc[c] = __builtin_amdgcn_mfma_f32_16x16x32_bf16(af, bf_, acc[c], 0, 0, 0);
        }
    }

    // s/d partials from f32 accumulators
    float avs[4], avd[4];
    #pragma unroll
    for (int c = 0; c < 4; ++c) {
        avs[c] = a[wc0 + c * 16 + lr];
        avd[c] = a[DD + wc0 + c * 16 + lr];
    }
    #pragma unroll
    for (int i = 0; i < 4; ++i) {
        float ps = 0.f, pd = 0.f;
        #pragma unroll
        for (int c = 0; c < 4; ++c) {
            ps = fmaf(acc[c][i], avs[c], ps);
            pd = fmaf(acc[c][i], avd[c], pd);
        }
        #pragma unroll
        for (int o = 8; o > 0; o >>= 1) {
            ps += __shfl_xor(ps, o);
            pd += __shfl_xor(pd, o);
        }
        if (lr == 0) {
            int brow = wr0 + lk * 4 + i;
            atomicAdd(&sdl[brow], ps);
            atomicAdd(&sdl[GROWS + brow], pd);
        }
    }
    // h -> LDS (bf16)
    #pragma unroll
    for (int c = 0; c < 4; ++c)
        #pragma unroll
        for (int i = 0; i < 4; ++i)
            hs[wr0 + lk * 4 + i][wc0 + c * 16 + lr] = f2bf(acc[c][i]);
    __syncthreads();

    // coalesced writeback: thread t -> row t>>3, cols (t&7)*16 .. +16
    {
        int row = t >> 3, colg = (t & 7) * 16;
        int grow = r0 + row;
        if (grow < NN) {
            ushort8 v0 = *(const ushort8*)&hs[row][colg];
            ushort8 v1 = *(const ushort8*)&hs[row][colg + 8];
            *(ushort8*)(hb + (size_t)grow * DD + colg) = v0;
            *(ushort8*)(hb + (size_t)grow * DD + colg + 8) = v1;
        }
    }
    if (t < GROWS) {
        int grow = r0 + t;
        if (grow < NN) { sArr[grow] = sdl[t]; dArr[grow] = sdl[GROWS + t]; }
    }
}

// ---------- bscat: slab scatter. record .x = (dlocal<<16)|src, .y = e bits ----------
__global__ __launch_bounds__(256) void bscat_k(const int* __restrict__ src,
                                               const int* __restrict__ dst,
                                               const float* __restrict__ sA,
                                               const float* __restrict__ dA,
                                               int* __restrict__ cntg,
                                               int* __restrict__ spill_cnt,
                                               uint2* __restrict__ rec,
                                               uint4* __restrict__ spill) {
    __shared__ int lh[NBKT];
    __shared__ int gb[NBKT];
    int t = threadIdx.x;
    for (int k = t; k < NBKT; k += 256) lh[k] = 0;
    __syncthreads();
    int base = blockIdx.x * BCH;
    unsigned pk[16]; int bk[16]; float ev[16];
    #pragma unroll
    for (int i = 0; i < 16; ++i) {
        int idx = base + i * 256 + t;
        if (idx < NE) {
            int s_ = src[idx], d_ = dst[idx];
            bk[i] = d_ >> 6;
            pk[i] = ((unsigned)(d_ & 63) << 16) | (unsigned)s_;
            float z = sA[s_] + dA[d_];
            ev[i] = 1.f / (1.f + __expf(-z));
            atomicAdd(&lh[bk[i]], 1);
        } else bk[i] = -1;
    }
    __syncthreads();
    for (int k = t; k < NBKT; k += 256) {
        int c = lh[k];
        lh[k] = 0;                       // becomes local cursor
        if (c) gb[k] = atomicAdd(&cntg[k], c);
    }
    __syncthreads();
    #pragma unroll
    for (int i = 0; i < 16; ++i) {
        if (bk[i] >= 0) {
            int sl = atomicAdd(&lh[bk[i]], 1);
            int p = gb[bk[i]] + sl;
            if (p < CAP) {
                rec[(size_t)bk[i] * CAP + p] = make_uint2(pk[i], __float_as_uint(ev[i]));
            } else {
                int sp = atomicAdd(spill_cnt, 1);
                if (sp < SPILL_CAP)
                    spill[sp] = make_uint4(pk[i] & 0xffffu,
                                           (unsigned)(bk[i] * 64 + (int)(pk[i] >> 16)),
                                           __float_as_uint(ev[i]), 0u);
            }
        }
    }
}

// ---------- agg: one 512-thread WG per bucket; LDS node-sort then per-node wave gather ----------
__global__ __launch_bounds__(512) void bsort_agg_k(const uint32_t* __restrict__ hb,
                                                   const int* __restrict__ cntg,
                                                   const uint2* __restrict__ rec,
                                                   float* __restrict__ out) {
    __shared__ uint2 srt[CAP];      // 10 KB
    __shared__ int h64[64];
    __shared__ int s65[65];
    __shared__ int curw[64];
    int t = threadIdx.x, l = t & 63, wid = t >> 6;
    int b = blockIdx.x;
    int cnt = cntg[b]; if (cnt > CAP) cnt = CAP;
    int beg = b * CAP;
    int n0 = b * 64;
    if (t < 64) h64[t] = 0;
    __syncthreads();

    for (int j = t; j < cnt; j += 512) {
        uint2 r = rec[beg + j];
        atomicAdd(&h64[r.x >> 16], 1);
    }
    __syncthreads();
    if (wid == 0) {
        int v = h64[l];
        int inc = v;
        #pragma unroll
        for (int o = 1; o < 64; o <<= 1) {
            int nb = __shfl_up(inc, o);
            if (l >= o) inc += nb;
        }
        s65[l + 1] = inc;
        if (l == 0) s65[0] = 0;
        curw[l] = inc - v;
    }
    __syncthreads();
    for (int j = t; j < cnt; j += 512) {
        uint2 r = rec[beg + j];
        int p = atomicAdd(&curw[r.x >> 16], 1);
        srt[p] = r;
    }
    __syncthreads();
    #pragma unroll 1
    for (int rr = 0; rr < 8; ++rr) {
        int d = wid * 8 + rr;
        int n = n0 + d;
        if (n >= NN) break;
        int js = s65[d], je = s65[d + 1];
        float2 a0 = {0.f,0.f}, a1 = {0.f,0.f}, a2 = {0.f,0.f}, a3 = {0.f,0.f};
        int j = js;
        for (; j + 3 < je; j += 4) {
            uint2 r0 = srt[j], r1 = srt[j+1], r2 = srt[j+2], r3 = srt[j+3];
            uint32_t u0 = hb[(size_t)(r0.x & 0xffffu) * 64 + l];
            uint32_t u1 = hb[(size_t)(r1.x & 0xffffu) * 64 + l];
            uint32_t u2 = hb[(size_t)(r2.x & 0xffffu) * 64 + l];
            uint32_t u3 = hb[(size_t)(r3.x & 0xffffu) * 64 + l];
            float e0 = __uint_as_float(r0.y), e1 = __uint_as_float(r1.y);
            float e2 = __uint_as_float(r2.y), e3 = __uint_as_float(r3.y);
            a0.x = fmaf(e0, bf_lo(u0), a0.x); a0.y = fmaf(e0, bf_hi(u0), a0.y);
            a1.x = fmaf(e1, bf_lo(u1), a1.x); a1.y = fmaf(e1, bf_hi(u1), a1.y);
            a2.x = fmaf(e2, bf_lo(u2), a2.x); a2.y = fmaf(e2, bf_hi(u2), a2.y);
            a3.x = fmaf(e3, bf_lo(u3), a3.x); a3.y = fmaf(e3, bf_hi(u3), a3.y);
        }
        for (; j < je; ++j) {
            uint2 r0 = srt[j];
            uint32_t u0 = hb[(size_t)(r0.x & 0xffffu) * 64 + l];
            float e0 = __uint_as_float(r0.y);
            a0.x = fmaf(e0, bf_lo(u0), a0.x); a0.y = fmaf(e0, bf_hi(u0), a0.y);
        }
        float2 res;
        res.x = (a0.x + a1.x) + (a2.x + a3.x);
        res.y = (a0.y + a1.y) + (a2.y + a3.y);
        ((float2*)out)[(size_t)n * 64 + l] = res;
    }
}

// ---------- spill drain (normally 0 records) ----------
__global__ __launch_bounds__(256) void spill_k(const int* __restrict__ spill_cnt,
                                               const uint4* __restrict__ spill,
                                               const uint32_t* __restrict__ hb,
                                               float* __restrict__ out) {
    int n = *spill_cnt; if (n > SPILL_CAP) n = SPILL_CAP;
    int w = blockIdx.x * 4 + (threadIdx.x >> 6), l = threadIdx.x & 63;
    for (int i = w; i < n; i += 32) {
        uint4 r = spill[i];
        uint32_t u = hb[(size_t)r.x * 64 + l];
        float e = __uint_as_float(r.z);
        atomicAdd(&out[(size_t)r.y * DD + 2 * l],     e * bf_lo(u));
        atomicAdd(&out[(size_t)r.y * DD + 2 * l + 1], e * bf_hi(u));
    }
}

// ---------- fallback: direct atomic scatter-add ----------
__global__ __launch_bounds__(256) void edge_atomic_k(const int* __restrict__ src, const int* __restrict__ dst,
                                                     const float* __restrict__ sArr, const float* __restrict__ dArr,
                                                     const uint32_t* __restrict__ hb, float* __restrict__ out) {
    int wid = threadIdx.x >> 6, l = threadIdx.x & 63;
    int e = blockIdx.x * 4 + wid;
    if (e >= NE) return;
    int sv = src[e], dv = dst[e];
    float z = sArr[sv] + dArr[dv];
    float ev = 1.0f / (1.0f + __expf(-z));
    uint32_t u = hb[(size_t)sv * 64 + l];
    atomicAdd(&out[(size_t)dv * DD + 2 * l],     ev * bf_lo(u));
    atomicAdd(&out[(size_t)dv * DD + 2 * l + 1], ev * bf_hi(u));
}

extern "C" void kernel_launch(void* const* d_in, const int* in_sizes, int n_in,
                              void* d_out, int out_size, void* d_ws, size_t ws_size,
                              hipStream_t stream) {
    const float* x  = (const float*)d_in[0];
    const float* W  = (const float*)d_in[1];
    const float* a  = (const float*)d_in[2];
    const int* src  = (const int*)d_in[3];
    const int* dst  = (const int*)d_in[4];
    float* out = (float*)d_out;

    char* p = (char*)d_ws;
    uint16_t* hb = (uint16_t*)p;            p += (size_t)NN * DD * 2;       // 12.8 MB
    uint16_t* Wb = (uint16_t*)p;            p += (size_t)DD * DD * 2;       // 32 KB
    float* sA    = (float*)p;               p += (size_t)NN * 4;
    float* dA    = (float*)p;               p += (size_t)NN * 4;
    int*   cntg  = (int*)p;                 p += (size_t)NBKT * 4;
    int*   scnt  = (int*)p;                 p += 16;
    uint2* rec   = (uint2*)(((uintptr_t)p + 15) & ~(uintptr_t)15);
    p = (char*)(rec + (size_t)NBKT * CAP);                                   // 8.0 MB
    uint4* spill = (uint4*)p;               p += (size_t)SPILL_CAP * 16;     // 0.5 MB
    size_t need  = (size_t)(p - (char*)d_ws);

    if (ws_size >= need) {
        wconv_k<<<64, 256, 0, stream>>>(W, Wb, cntg);    // also zeros cntg+scnt
        gemm_mfma_k<<<GGRID, 256, 0, stream>>>(x, Wb, a, hb, sA, dA);
        bscat_k<<<BGRID, 256, 0, stream>>>(src, dst, sA, dA, cntg, scnt, rec, spill);
        bsort_agg_k<<<NBKT, 512, 0, stream>>>((const uint32_t*)hb, cntg, rec, out);
        spill_k<<<8, 256, 0, stream>>>(scnt, spill, (const uint32_t*)hb, out);
    } else {
        hipMemsetAsync(out, 0, sizeof(float) * (size_t)NN * DD, stream);
        wconv_k<<<64, 256, 0, stream>>>(W, Wb, cntg);
        gemm_mfma_k<<<GGRID, 256, 0, stream>>>(x, Wb, a, hb, sA, dA);
        edge_atomic_k<<<NE / 4, 256, 0, stream>>>(src, dst, sA, dA, (const uint32_t*)hb, out);
    }
}

// Round 8
// 85.924 us; speedup vs baseline: 8.9447x; 1.0247x over previous
//
#include <hip/hip_runtime.h>
#include <hip/hip_bf16.h>
#include <stdint.h>

#define NN 50000
#define NE 800000
#define DD 128
#define NBKT 782         // ceil(NN/64) dst buckets of 64 nodes
#define BCH 4096         // edges per workgroup in bscat
#define BGRID ((NE + BCH - 1) / BCH)   // 196
#define CAP 1280         // per-bucket slab capacity (mean 1023, sigma ~32)
#define SPILL_CAP 32768
#define GROWS 32         // gemm rows per block
#define GGRID ((NN + GROWS - 1) / GROWS)  // 1563

typedef __attribute__((ext_vector_type(8))) unsigned short ushort8;
typedef __attribute__((ext_vector_type(8))) short short8;
typedef __attribute__((ext_vector_type(4))) float f32x4;

__device__ inline uint16_t f2bf(float f) {            // RNE f32->bf16
    uint32_t u = __float_as_uint(f);
    return (uint16_t)((u + 0x7fffu + ((u >> 16) & 1u)) >> 16);
}
__device__ inline float bf_lo(uint32_t u) { return __uint_as_float(u << 16); }
__device__ inline float bf_hi(uint32_t u) { return __uint_as_float(u & 0xffff0000u); }

// ---------- W f32 -> bf16 (row-major [j][k]) + zero the bucket counters ----------
__global__ __launch_bounds__(256) void wconv_k(const float* __restrict__ W,
                                               uint16_t* __restrict__ Wb,
                                               int* __restrict__ cntg) {
    int t = threadIdx.x;
    if (blockIdx.x == 0) {                         // zero cntg[NBKT] + scnt (contiguous)
        for (int k = t; k < NBKT + 4; k += 256) cntg[k] = 0;
    }
    int i = blockIdx.x * 256 + t;
    if (i < DD * DD) Wb[i] = f2bf(W[i]);
}

// ---------- MFMA GEMM: h = x @ W^T (bf16 mfma, f32 acc) + s/d projections ----------
__global__ __launch_bounds__(256) void gemm_mfma_k(const float* __restrict__ x,
                                                   const uint16_t* __restrict__ Wb,
                                                   const float* __restrict__ a,
                                                   uint16_t* __restrict__ hb,
                                                   float* __restrict__ sArr,
                                                   float* __restrict__ dArr) {
    __shared__ __align__(16) uint16_t hs[GROWS][136];   // padded: +8 bf16/row
    __shared__ float sdl[2 * GROWS];
    const int t = threadIdx.x, l = t & 63, wid = t >> 6;
    const int r0 = blockIdx.x * GROWS;
    const int wr0 = (wid >> 1) * 16;
    const int wc0 = (wid & 1) * 64;
    const int lr = l & 15, lk = l >> 4;
    if (t < 2 * GROWS) sdl[t] = 0.f;
    __syncthreads();

    f32x4 acc[4] = {{0.f,0.f,0.f,0.f},{0.f,0.f,0.f,0.f},{0.f,0.f,0.f,0.f},{0.f,0.f,0.f,0.f}};
    const int arow = r0 + wr0 + lr;
    const bool rok = arow < NN;
    const float* xp = x + (size_t)arow * DD + lk * 8;

    #pragma unroll
    for (int kc = 0; kc < 4; ++kc) {
        short8 af;
        if (rok) {
            float4 v0 = *(const float4*)(xp + kc * 32);
            float4 v1 = *(const float4*)(xp + kc * 32 + 4);
            af[0] = (short)f2bf(v0.x); af[1] = (short)f2bf(v0.y);
            af[2] = (short)f2bf(v0.z); af[3] = (short)f2bf(v0.w);
            af[4] = (short)f2bf(v1.x); af[5] = (short)f2bf(v1.y);
            af[6] = (short)f2bf(v1.z); af[7] = (short)f2bf(v1.w);
        } else {
            af = short8{0,0,0,0,0,0,0,0};
        }
        #pragma unroll
        for (int c = 0; c < 4; ++c) {
            int col = wc0 + c * 16 + lr;
            short8 bf_ = *(const short8*)(Wb + (size_t)col * DD + kc * 32 + lk * 8);
            acc[c] = __builtin_amdgcn_mfma_f32_16x16x32_bf16(af, bf_, acc[c], 0, 0, 0);
        }
    }

    // s/d partials from f32 accumulators
    float avs[4], avd[4];
    #pragma unroll
    for (int c = 0; c < 4; ++c) {
        avs[c] = a[wc0 + c * 16 + lr];
        avd[c] = a[DD + wc0 + c * 16 + lr];
    }
    #pragma unroll
    for (int i = 0; i < 4; ++i) {
        float ps = 0.f, pd = 0.f;
        #pragma unroll
        for (int c = 0; c < 4; ++c) {
            ps = fmaf(acc[c][i], avs[c], ps);
            pd = fmaf(acc[c][i], avd[c], pd);
        }
        #pragma unroll
        for (int o = 8; o > 0; o >>= 1) {
            ps += __shfl_xor(ps, o);
            pd += __shfl_xor(pd, o);
        }
        if (lr == 0) {
            int brow = wr0 + lk * 4 + i;
            atomicAdd(&sdl[brow], ps);
            atomicAdd(&sdl[GROWS + brow], pd);
        }
    }
    // h -> LDS (bf16)
    #pragma unroll
    for (int c = 0; c < 4; ++c)
        #pragma unroll
        for (int i = 0; i < 4; ++i)
            hs[wr0 + lk * 4 + i][wc0 + c * 16 + lr] = f2bf(acc[c][i]);
    __syncthreads();

    // coalesced writeback: thread t -> row t>>3, cols (t&7)*16 .. +16
    {
        int row = t >> 3, colg = (t & 7) * 16;
        int grow = r0 + row;
        if (grow < NN) {
            ushort8 v0 = *(const ushort8*)&hs[row][colg];
            ushort8 v1 = *(const ushort8*)&hs[row][colg + 8];
            *(ushort8*)(hb + (size_t)grow * DD + colg) = v0;
            *(ushort8*)(hb + (size_t)grow * DD + colg + 8) = v1;
        }
    }
    if (t < GROWS) {
        int grow = r0 + t;
        if (grow < NN) { sArr[grow] = sdl[t]; dArr[grow] = sdl[GROWS + t]; }
    }
}

// ---------- bscat: slim slab scatter of 4B records. rec = (dlocal<<16)|src ----------
__global__ __launch_bounds__(256) void bscat_k(const int* __restrict__ src,
                                               const int* __restrict__ dst,
                                               int* __restrict__ cntg,
                                               int* __restrict__ spill_cnt,
                                               uint32_t* __restrict__ rec,
                                               uint2* __restrict__ spill) {
    __shared__ int lh[NBKT];
    __shared__ int gb[NBKT];
    int t = threadIdx.x;
    for (int k = t; k < NBKT; k += 256) lh[k] = 0;
    __syncthreads();
    int base = blockIdx.x * BCH;
    unsigned pk[16]; int bk[16];
    #pragma unroll
    for (int i = 0; i < 16; ++i) {
        int idx = base + i * 256 + t;
        if (idx < NE) {
            int s_ = src[idx], d_ = dst[idx];
            bk[i] = d_ >> 6;
            pk[i] = ((unsigned)(d_ & 63) << 16) | (unsigned)s_;
            atomicAdd(&lh[bk[i]], 1);
        } else bk[i] = -1;
    }
    __syncthreads();
    for (int k = t; k < NBKT; k += 256) {
        int c = lh[k];
        lh[k] = 0;                       // becomes local cursor
        if (c) gb[k] = atomicAdd(&cntg[k], c);
    }
    __syncthreads();
    #pragma unroll
    for (int i = 0; i < 16; ++i) {
        if (bk[i] >= 0) {
            int sl = atomicAdd(&lh[bk[i]], 1);
            int p = gb[bk[i]] + sl;
            if (p < CAP) {
                rec[(size_t)bk[i] * CAP + p] = pk[i];
            } else {
                int sp = atomicAdd(spill_cnt, 1);
                if (sp < SPILL_CAP)
                    spill[sp] = make_uint2(pk[i] & 0xffffu,
                                           (unsigned)(bk[i] * 64 + (int)(pk[i] >> 16)));
            }
        }
    }
}

// ---------- agg: one 512-thread WG per bucket; LDS sort + fused e-compute ----------
__global__ __launch_bounds__(512) void bsort_agg_k(const uint32_t* __restrict__ hb,
                                                   const float* __restrict__ sA,
                                                   const float* __restrict__ dA,
                                                   const int* __restrict__ cntg,
                                                   const uint32_t* __restrict__ rec,
                                                   float* __restrict__ out) {
    __shared__ uint32_t srt[CAP];   // 5 KB
    __shared__ float    eL[CAP];    // 5 KB
    __shared__ float dAl[64];
    __shared__ int h64[64];
    __shared__ int s65[65];
    __shared__ int curw[64];
    int t = threadIdx.x, l = t & 63, wid = t >> 6;
    int b = blockIdx.x;
    int cnt = cntg[b]; if (cnt > CAP) cnt = CAP;
    int beg = b * CAP;
    int n0 = b * 64;
    if (t < 64) {
        h64[t] = 0;
        int n = n0 + t;
        dAl[t] = (n < NN) ? dA[n] : 0.f;
    }
    __syncthreads();

    // histogram (cache records in registers: cnt<=1280 -> <=3 per thread)
    uint32_t rc[3]; int nrc = 0;
    for (int j = t; j < cnt; j += 512) {
        uint32_t r = rec[beg + j];
        rc[nrc++] = r;
        atomicAdd(&h64[r >> 16], 1);
    }
    __syncthreads();
    if (wid == 0) {
        int v = h64[l];
        int inc = v;
        #pragma unroll
        for (int o = 1; o < 64; o <<= 1) {
            int nb = __shfl_up(inc, o);
            if (l >= o) inc += nb;
        }
        s65[l + 1] = inc;
        if (l == 0) s65[0] = 0;
        curw[l] = inc - v;
    }
    __syncthreads();
    // scatter + fused sigmoid (once per record, one thread each)
    for (int k = 0; k < nrc; ++k) {
        uint32_t r = rc[k];
        int d = (int)(r >> 16);
        int p = atomicAdd(&curw[d], 1);
        float z = sA[r & 0xffffu] + dAl[d];
        srt[p] = r;
        eL[p] = 1.f / (1.f + __expf(-z));
    }
    __syncthreads();
    #pragma unroll 1
    for (int rr = 0; rr < 8; ++rr) {
        int d = wid * 8 + rr;
        int n = n0 + d;
        if (n >= NN) break;
        int js = s65[d], je = s65[d + 1];
        float2 a0 = {0.f,0.f}, a1 = {0.f,0.f}, a2 = {0.f,0.f}, a3 = {0.f,0.f};
        int j = js;
        for (; j + 3 < je; j += 4) {
            uint32_t r0 = srt[j], r1 = srt[j+1], r2 = srt[j+2], r3 = srt[j+3];
            float e0 = eL[j], e1 = eL[j+1], e2 = eL[j+2], e3 = eL[j+3];
            uint32_t u0 = hb[(size_t)(r0 & 0xffffu) * 64 + l];
            uint32_t u1 = hb[(size_t)(r1 & 0xffffu) * 64 + l];
            uint32_t u2 = hb[(size_t)(r2 & 0xffffu) * 64 + l];
            uint32_t u3 = hb[(size_t)(r3 & 0xffffu) * 64 + l];
            a0.x = fmaf(e0, bf_lo(u0), a0.x); a0.y = fmaf(e0, bf_hi(u0), a0.y);
            a1.x = fmaf(e1, bf_lo(u1), a1.x); a1.y = fmaf(e1, bf_hi(u1), a1.y);
            a2.x = fmaf(e2, bf_lo(u2), a2.x); a2.y = fmaf(e2, bf_hi(u2), a2.y);
            a3.x = fmaf(e3, bf_lo(u3), a3.x); a3.y = fmaf(e3, bf_hi(u3), a3.y);
        }
        for (; j < je; ++j) {
            uint32_t r0 = srt[j];
            float e0 = eL[j];
            uint32_t u0 = hb[(size_t)(r0 & 0xffffu) * 64 + l];
            a0.x = fmaf(e0, bf_lo(u0), a0.x); a0.y = fmaf(e0, bf_hi(u0), a0.y);
        }
        float2 res;
        res.x = (a0.x + a1.x) + (a2.x + a3.x);
        res.y = (a0.y + a1.y) + (a2.y + a3.y);
        ((float2*)out)[(size_t)n * 64 + l] = res;
    }
}

// ---------- spill drain (normally 0 records) ----------
__global__ __launch_bounds__(256) void spill_k(const int* __restrict__ spill_cnt,
                                               const uint2* __restrict__ spill,
                                               const float* __restrict__ sA,
                                               const float* __restrict__ dA,
                                               const uint32_t* __restrict__ hb,
                                               float* __restrict__ out) {
    int n = *spill_cnt; if (n > SPILL_CAP) n = SPILL_CAP;
    int w = blockIdx.x * 4 + (threadIdx.x >> 6), l = threadIdx.x & 63;
    for (int i = w; i < n; i += 32) {
        uint2 r = spill[i];
        float z = sA[r.x] + dA[r.y];
        float e = 1.f / (1.f + __expf(-z));
        uint32_t u = hb[(size_t)r.x * 64 + l];
        atomicAdd(&out[(size_t)r.y * DD + 2 * l],     e * bf_lo(u));
        atomicAdd(&out[(size_t)r.y * DD + 2 * l + 1], e * bf_hi(u));
    }
}

// ---------- fallback: direct atomic scatter-add ----------
__global__ __launch_bounds__(256) void edge_atomic_k(const int* __restrict__ src, const int* __restrict__ dst,
                                                     const float* __restrict__ sArr, const float* __restrict__ dArr,
                                                     const uint32_t* __restrict__ hb, float* __restrict__ out) {
    int wid = threadIdx.x >> 6, l = threadIdx.x & 63;
    int e = blockIdx.x * 4 + wid;
    if (e >= NE) return;
    int sv = src[e], dv = dst[e];
    float z = sArr[sv] + dArr[dv];
    float ev = 1.0f / (1.0f + __expf(-z));
    uint32_t u = hb[(size_t)sv * 64 + l];
    atomicAdd(&out[(size_t)dv * DD + 2 * l],     ev * bf_lo(u));
    atomicAdd(&out[(size_t)dv * DD + 2 * l + 1], ev * bf_hi(u));
}

extern "C" void kernel_launch(void* const* d_in, const int* in_sizes, int n_in,
                              void* d_out, int out_size, void* d_ws, size_t ws_size,
                              hipStream_t stream) {
    const float* x  = (const float*)d_in[0];
    const float* W  = (const float*)d_in[1];
    const float* a  = (const float*)d_in[2];
    const int* src  = (const int*)d_in[3];
    const int* dst  = (const int*)d_in[4];
    float* out = (float*)d_out;

    char* p = (char*)d_ws;
    uint16_t* hb = (uint16_t*)p;            p += (size_t)NN * DD * 2;       // 12.8 MB
    uint16_t* Wb = (uint16_t*)p;            p += (size_t)DD * DD * 2;       // 32 KB
    float* sA    = (float*)p;               p += (size_t)NN * 4;
    float* dA    = (float*)p;               p += (size_t)NN * 4;
    int*   cntg  = (int*)p;                 p += (size_t)NBKT * 4;
    int*   scnt  = (int*)p;                 p += 16;
    uint32_t* rec = (uint32_t*)(((uintptr_t)p + 15) & ~(uintptr_t)15);
    p = (char*)(rec + (size_t)NBKT * CAP);                                   // 4.0 MB
    uint2* spill = (uint2*)p;               p += (size_t)SPILL_CAP * 8;      // 0.25 MB
    size_t need  = (size_t)(p - (char*)d_ws);

    if (ws_size >= need) {
        wconv_k<<<64, 256, 0, stream>>>(W, Wb, cntg);    // also zeros cntg+scnt
        gemm_mfma_k<<<GGRID, 256, 0, stream>>>(x, Wb, a, hb, sA, dA);
        bscat_k<<<BGRID, 256, 0, stream>>>(src, dst, cntg, scnt, rec, spill);
        bsort_agg_k<<<NBKT, 512, 0, stream>>>((const uint32_t*)hb, sA, dA, cntg, rec, out);
        spill_k<<<8, 256, 0, stream>>>(scnt, spill, sA, dA, (const uint32_t*)hb, out);
    } else {
        hipMemsetAsync(out, 0, sizeof(float) * (size_t)NN * DD, stream);
        wconv_k<<<64, 256, 0, stream>>>(W, Wb, cntg);
        gemm_mfma_k<<<GGRID, 256, 0, stream>>>(x, Wb, a, hb, sA, dA);
        edge_atomic_k<<<NE / 4, 256, 0, stream>>>(src, dst, sA, dA, (const uint32_t*)hb, out);
    }
}